// Round 13
// baseline (465.224 us; speedup 1.0000x reference)
//
#include <hip/hip_runtime.h>
#include <hip/hip_bf16.h>
#include <math.h>

#define B_ 2
#define T_ 2048
#define C_ 768
#define H_ 12
#define D_ 64
#define HID_ 3072
#define NROW 4096   // B*T
#define N3C 2304    // 3*C

typedef short bf16x8 __attribute__((ext_vector_type(8)));
typedef float f32x4 __attribute__((ext_vector_type(4)));
typedef unsigned short u16;
typedef unsigned int u32;

__device__ inline u16 f2bf(float f) {
    u32 u = __float_as_uint(f);
    u32 r = (u + 0x7fffu + ((u >> 16) & 1u)) >> 16;  // RNE
    return (u16)r;
}

__device__ __forceinline__ void dma16(const void* g, void* lds) {
    // each lane: 16B from its own g -> wave-uniform lds base + lane*16 (linear)
    __builtin_amdgcn_global_load_lds(
        (const __attribute__((address_space(1))) void*)g,
        (__attribute__((address_space(3))) void*)lds, 16, 0, 0);
}

// ---------------- fused weight convert: all 4 weight matrices in one launch ----------------
__global__ __launch_bounds__(256) void cvt4_kernel(const float* __restrict__ s0, u16* __restrict__ d0, int n0,
                                                   const float* __restrict__ s1, u16* __restrict__ d1, int n1,
                                                   const float* __restrict__ s2, u16* __restrict__ d2, int n2,
                                                   const float* __restrict__ s3, u16* __restrict__ d3, int n3) {
    int i = (blockIdx.x * 256 + threadIdx.x) * 4;
    const float* s;
    u16* d;
    if (i < n0) { s = s0; d = d0; }
    else if ((i -= n0) < n1) { s = s1; d = d1; }
    else if ((i -= n1) < n2) { s = s2; d = d2; }
    else if ((i -= n2) < n3) { s = s3; d = d3; }
    else return;
    float4 v = *(const float4*)(s + i);
    ushort4 o;
    o.x = f2bf(v.x); o.y = f2bf(v.y); o.z = f2bf(v.z); o.w = f2bf(v.w);
    *(ushort4*)(d + i) = o;
}

// ---------------- LayerNorm (f32 in, bf16 out), one block per row ----------------
__global__ __launch_bounds__(256) void ln_kernel(const float* __restrict__ x,
                                                 const float* __restrict__ g,
                                                 const float* __restrict__ b,
                                                 u16* __restrict__ out) {
    int row = blockIdx.x, t = threadIdx.x;
    const float* xr = x + (size_t)row * C_;
    float v[3], s = 0.f, sq = 0.f;
#pragma unroll
    for (int i = 0; i < 3; i++) {
        v[i] = xr[i * 256 + t];
        s += v[i]; sq += v[i] * v[i];
    }
    for (int m = 32; m; m >>= 1) { s += __shfl_xor(s, m); sq += __shfl_xor(sq, m); }
    __shared__ float ss[4], ssq[4];
    int wid = t >> 6;
    if ((t & 63) == 0) { ss[wid] = s; ssq[wid] = sq; }
    __syncthreads();
    s = ss[0] + ss[1] + ss[2] + ss[3];
    sq = ssq[0] + ssq[1] + ssq[2] + ssq[3];
    float mu = s * (1.f / C_);
    float var = sq * (1.f / C_) - mu * mu;
    float rstd = rsqrtf(var + 1e-5f);
#pragma unroll
    for (int i = 0; i < 3; i++) {
        int c = i * 256 + t;
        out[(size_t)row * C_ + c] = f2bf((v[i] - mu) * rstd * g[c] + b[c]);
    }
}

// ---------------- bf16 MFMA GEMM: global_load_lds staging with PRE-SWIZZLED ----------------
// global source (m201 stage_rc / rule 21: linear LDS dest + inverse-swz source
// + swz read). R11's regression was one-sided swizzle (linear reads -> 16-way
// conflict); here reads keep R12's conflict-free XOR pattern while staging
// goes through the zero-VGPR DMA path (m151: 874 vs 646 TF).
template <int EPI>
__global__ __launch_bounds__(256) void gemm_kernel(const u16* __restrict__ A,
                                                   const u16* __restrict__ W,
                                                   const float* __restrict__ bias,
                                                   float* __restrict__ outf,
                                                   u16* __restrict__ outb,
                                                   const float* __restrict__ res,
                                                   const float* __restrict__ ls,
                                                   int N, int K) {
    __shared__ u16 Alds[128 * 64];
    __shared__ u16 Blds[128 * 64];
    int tid = threadIdx.x;
    int m0 = blockIdx.y * 128, n0 = blockIdx.x * 128;
    int lane = tid & 63, wid = tid >> 6;
    int wr = wid >> 1, wc = wid & 1;
    int lr = lane & 15, lq = lane >> 4;

    f32x4 acc[4][4];
#pragma unroll
    for (int i = 0; i < 4; i++)
#pragma unroll
        for (int j = 0; j < 4; j++) acc[i][j] = (f32x4){0.f, 0.f, 0.f, 0.f};

    int nk = K >> 6;
    const u16* Ab = A + (size_t)m0 * K;
    const u16* Wb = W + (size_t)n0 * K;

    for (int kt = 0; kt < nk; ++kt) {
        int k0 = kt << 6;
        __syncthreads();                 // previous compute done before overwrite
#pragma unroll
        for (int i = 0; i < 4; i++) {
            int c = tid + i * 256, row = c >> 3, j = c & 7;
            int js = j ^ (row & 7);      // inverse-swizzled SOURCE chunk (same 128B segment)
            // linear LDS dest: chunk c at byte c*16; wave-uniform base + lane*16
            dma16(Ab + (size_t)row * K + k0 + js * 8, Alds + (i * 256 + wid * 64) * 8);
            dma16(Wb + (size_t)row * K + k0 + js * 8, Blds + (i * 256 + wid * 64) * 8);
        }
        __syncthreads();                 // compiler drains vmcnt before barrier
#pragma unroll
        for (int s = 0; s < 2; s++) {
            bf16x8 af[4], bw[4];
#pragma unroll
            for (int i = 0; i < 4; i++) {
                int arow = wr * 64 + i * 16 + lr;
                af[i] = *(const bf16x8*)(Alds + arow * 64 + (((4 * s + lq) ^ (arow & 7)) << 3));
                int brow = wc * 64 + i * 16 + lr;
                bw[i] = *(const bf16x8*)(Blds + brow * 64 + (((4 * s + lq) ^ (brow & 7)) << 3));
            }
#pragma unroll
            for (int i = 0; i < 4; i++)
#pragma unroll
                for (int j = 0; j < 4; j++)
                    acc[i][j] = __builtin_amdgcn_mfma_f32_16x16x32_bf16(af[i], bw[j], acc[i][j], 0, 0, 0);
        }
    }
#pragma unroll
    for (int i = 0; i < 4; i++) {
#pragma unroll
        for (int j = 0; j < 4; j++) {
#pragma unroll
            for (int r = 0; r < 4; r++) {
                int gm = m0 + wr * 64 + i * 16 + lq * 4 + r;
                int gn = n0 + wc * 64 + j * 16 + lr;
                float val = acc[i][j][r] + bias[gn];
                if (EPI == 0) {
                    outb[(size_t)gm * N + gn] = f2bf(val);
                } else if (EPI == 1) {
                    float gl = 0.5f * val * (1.f + erff(val * 0.70710678118654752f));
                    outb[(size_t)gm * N + gn] = f2bf(gl);
                } else {
                    outf[(size_t)gm * N + gn] = res[(size_t)gm * N + gn] + ls[gn] * val;
                }
            }
        }
    }
}

// ---------------- V transpose: qkv_buf v-part -> Vt [B,H,D,T] ----------------
__global__ __launch_bounds__(256) void vtrans_kernel(const u16* __restrict__ qkv,
                                                     u16* __restrict__ vt) {
    __shared__ u16 tile[64 * 72];
    int t0 = blockIdx.x * 64, h = blockIdx.y, b = blockIdx.z;
    int tid = threadIdx.x;
#pragma unroll
    for (int i = 0; i < 2; i++) {
        int c = tid + i * 256, tr = c >> 3, j = c & 7;
        bf16x8 v = *(const bf16x8*)(qkv + (size_t)(b * T_ + t0 + tr) * N3C + 1536 + h * 64 + j * 8);
        *(bf16x8*)(tile + tr * 72 + j * 8) = v;
    }
    __syncthreads();
#pragma unroll
    for (int i = 0; i < 2; i++) {
        int c = tid + i * 256, d = c >> 3, tj = c & 7;
        bf16x8 o;
#pragma unroll
        for (int k = 0; k < 8; k++) o[k] = (short)tile[(tj * 8 + k) * 72 + d];
        *(bf16x8*)(vt + (size_t)((b * H_ + h) * 64 + d) * T_ + t0 + tj * 8) = o;
    }
}

// ---------------- fused attention (R10 winner: R6 structure + NT streams) ----------------
__global__ __launch_bounds__(256, 2) void attn_kernel(const u16* __restrict__ qkv,
                                                      const u16* __restrict__ vt,
                                                      const float* __restrict__ bias,
                                                      const float* __restrict__ mask,
                                                      float* __restrict__ attn_out,
                                                      u16* __restrict__ ybuf) {
    __shared__ u16 S[16 * 2048];     // bf16 scaled logits, then bf16 P in place
    __shared__ float rinv_lds[16];
    char* Sb = (char*)S;
    int qt = blockIdx.x, h = blockIdx.y, b = blockIdx.z;
    int tid = threadIdx.x, lane = tid & 63, wid = tid >> 6;
    int lr = lane & 15, lq = lane >> 4;
    int q0 = qt * 16;
    size_t bh = (size_t)(b * H_ + h);
    const float scale = 0.125f;

    // ---- A1: S = bf16(QK^T * scale) via swapped mfma(K,Q); wave w owns cols w*512.. ----
    const u16* qp = qkv + (size_t)(b * T_ + q0 + lr) * N3C + h * 64;
    bf16x8 qa0 = *(const bf16x8*)(qp + lq * 8);
    bf16x8 qa1 = *(const bf16x8*)(qp + 32 + lq * 8);
    const u16* kbase = qkv + (size_t)(b * T_ + wid * 512 + lr) * N3C + 768 + h * 64 + lq * 8;
#pragma unroll 4
    for (int ct = 0; ct < 32; ++ct) {
        bf16x8 kf0 = *(const bf16x8*)(kbase + (size_t)ct * 16 * N3C);
        bf16x8 kf1 = *(const bf16x8*)(kbase + (size_t)ct * 16 * N3C + 32);
        f32x4 a = (f32x4){0.f, 0.f, 0.f, 0.f};
        a = __builtin_amdgcn_mfma_f32_16x16x32_bf16(kf0, qa0, a, 0, 0, 0);
        a = __builtin_amdgcn_mfma_f32_16x16x32_bf16(kf1, qa1, a, 0, 0, 0);
        int colbase = wid * 512 + ct * 16;   // lane holds S[lr][colbase+lq*4 ..+3]
        ushort4 pk;
        pk.x = f2bf(a[0] * scale);
        pk.y = f2bf(a[1] * scale);
        pk.z = f2bf(a[2] * scale);
        pk.w = f2bf(a[3] * scale);
        *(ushort4*)(Sb + (((u32)lr * 4096 + 2 * colbase + 8 * lq) ^ ((lr & 7) << 4))) = pk;
    }
    __syncthreads();

    // ---- A2: P = exp(S + bias + mask), rows batched; bias via NT loads ----
    const float* bb = bias + (bh * T_ + q0 + wid * 4) * T_;
    const float* mb = mask + ((size_t)b * T_ + q0 + wid * 4) * T_;
    float lsum4[4] = {0.f, 0.f, 0.f, 0.f};
#pragma unroll
    for (int ch = 0; ch < 8; ++ch) {
        int col = ch * 256 + lane * 4;           // 64 lanes = 1KB contiguous per row
        f32x4 b4[4];
        float4 m4[4];
#pragma unroll
        for (int rr = 0; rr < 4; ++rr) {         // 8 independent dwordx4 loads issue here
            b4[rr] = __builtin_nontemporal_load((const f32x4*)(bb + (size_t)rr * T_ + col));
            m4[rr] = *(const float4*)(mb + (size_t)rr * T_ + col);
        }
#pragma unroll
        for (int rr = 0; rr < 4; ++rr) {
            int r = wid * 4 + rr;
            u32 addr = ((u32)r * 4096 + (u32)col * 2) ^ ((u32)(r & 7) << 4);
            uint2 s2 = *(const uint2*)(Sb + addr);
            float e0 = __expf(__uint_as_float(s2.x << 16) + b4[rr][0] + m4[rr].x);
            float e1 = __expf(__uint_as_float(s2.x & 0xffff0000u) + b4[rr][1] + m4[rr].y);
            float e2 = __expf(__uint_as_float(s2.y << 16) + b4[rr][2] + m4[rr].z);
            float e3 = __expf(__uint_as_float(s2.y & 0xffff0000u) + b4[rr][3] + m4[rr].w);
            lsum4[rr] += (e0 + e1) + (e2 + e3);
            uint2 o;
            o.x = ((u32)f2bf(e1) << 16) | (u32)f2bf(e0);
            o.y = ((u32)f2bf(e3) << 16) | (u32)f2bf(e2);
            *(uint2*)(Sb + addr) = o;                // in-place bf16 P
        }
    }
    float rinv_r[4];
#pragma unroll
    for (int rr = 0; rr < 4; ++rr) {
        float ls = lsum4[rr];
        for (int m = 32; m; m >>= 1) ls += __shfl_xor(ls, m);
        rinv_r[rr] = 1.f / ls;
        if (lane == 0) rinv_lds[wid * 4 + rr] = rinv_r[rr];
    }
    __syncthreads();

    // ---- A3: attn_out = P * rinv via NT stores (write-once stream) ----
    float* ao_base = attn_out + (bh * T_ + q0 + wid * 4) * T_;
#pragma unroll
    for (int ch = 0; ch < 8; ++ch) {
        int col = ch * 256 + lane * 4;
#pragma unroll
        for (int rr = 0; rr < 4; ++rr) {
            int r = wid * 4 + rr;
            u32 addr = ((u32)r * 4096 + (u32)col * 2) ^ ((u32)(r & 7) << 4);
            uint2 s2 = *(const uint2*)(Sb + addr);
            float rv = rinv_r[rr];
            f32x4 o;
            o[0] = __uint_as_float(s2.x << 16) * rv;
            o[1] = __uint_as_float(s2.x & 0xffff0000u) * rv;
            o[2] = __uint_as_float(s2.y << 16) * rv;
            o[3] = __uint_as_float(s2.y & 0xffff0000u) * rv;
            __builtin_nontemporal_store(o, (f32x4*)(ao_base + (size_t)rr * T_ + col));
        }
    }

    // ---- C: y = (P @ V) * rinv; wave w owns d-cols 16w..16w+15 ----
    f32x4 acc = (f32x4){0.f, 0.f, 0.f, 0.f};
    const u16* vtp = vt + (bh * 64 + wid * 16 + lr) * (size_t)T_ + lq * 8;
#pragma unroll 4
    for (int ks = 0; ks < 64; ++ks) {
        bf16x8 pf = *(const bf16x8*)(Sb + (((u32)lr * 4096 + ks * 64 + lq * 16) ^ ((lr & 7) << 4)));
        bf16x8 vf = *(const bf16x8*)(vtp + ks * 32);
        acc = __builtin_amdgcn_mfma_f32_16x16x32_bf16(pf, vf, acc, 0, 0, 0);
    }
#pragma unroll
    for (int r = 0; r < 4; r++) {
        int row = lq * 4 + r;
        float y = acc[r] * rinv_lds[row];
        ybuf[(size_t)(b * T_ + q0 + row) * C_ + h * 64 + wid * 16 + lr] = f2bf(y);
    }
}

// ---------------- host ----------------
extern "C" void kernel_launch(void* const* d_in, const int* in_sizes, int n_in,
                              void* d_out, int out_size, void* d_ws, size_t ws_size,
                              hipStream_t stream) {
    const float* x = (const float*)d_in[0];
    const float* mask = (const float*)d_in[1];
    const float* bias = (const float*)d_in[2];
    const float* ln1g = (const float*)d_in[3];
    const float* ln1b = (const float*)d_in[4];
    const float* qkvw = (const float*)d_in[5];
    const float* qkvb = (const float*)d_in[6];
    const float* projw = (const float*)d_in[7];
    const float* projb = (const float*)d_in[8];
    const float* ls1 = (const float*)d_in[9];
    const float* ln2g = (const float*)d_in[10];
    const float* ln2b = (const float*)d_in[11];
    const float* w1 = (const float*)d_in[12];
    const float* b1 = (const float*)d_in[13];
    const float* w2 = (const float*)d_in[14];
    const float* b2 = (const float*)d_in[15];
    const float* ls2 = (const float*)d_in[16];

    char* ws = (char*)d_ws;
    size_t off = 0;
    u16* qkvw_b = (u16*)(ws + off); off += (size_t)N3C * C_ * 2;
    u16* projw_b = (u16*)(ws + off); off += (size_t)C_ * C_ * 2;
    u16* w1_b = (u16*)(ws + off); off += (size_t)HID_ * C_ * 2;
    u16* w2_b = (u16*)(ws + off); off += (size_t)C_ * HID_ * 2;
    u16* xn = (u16*)(ws + off); off += (size_t)NROW * C_ * 2;          // reused as hn after attn
    u16* qkvbuf = (u16*)(ws + off); off += (size_t)NROW * N3C * 2;     // } contiguous; reused as
    u16* vt = (u16*)(ws + off); off += (size_t)B_ * H_ * D_ * T_ * 2;  // } g [4096,3072] after attn
    u16* g = qkvbuf;
    u16* ybuf = (u16*)(ws + off); off += (size_t)NROW * C_ * 2;
    float* x1 = (float*)(ws + off); off += (size_t)NROW * C_ * 4;
    (void)ws_size; (void)n_in; (void)in_sizes; (void)out_size;

    float* outx = (float*)d_out;
    float* attn_out = outx + (size_t)NROW * C_;

    // weights -> bf16 (single fused launch)
    {
        int n0 = N3C * C_, n1 = C_ * C_, n2 = HID_ * C_, n3 = C_ * HID_;
        int total = n0 + n1 + n2 + n3;
        cvt4_kernel<<<(total / 4 + 255) / 256, 256, 0, stream>>>(
            qkvw, qkvw_b, n0, projw, projw_b, n1, w1, w1_b, n2, w2, w2_b, n3);
    }

    // LN1
    ln_kernel<<<NROW, 256, 0, stream>>>(x, ln1g, ln1b, xn);
    // QKV
    gemm_kernel<0><<<dim3(N3C / 128, NROW / 128), 256, 0, stream>>>(
        xn, qkvw_b, qkvb, nullptr, qkvbuf, nullptr, nullptr, N3C, C_);
    // V transpose
    vtrans_kernel<<<dim3(T_ / 64, H_, B_), 256, 0, stream>>>(qkvbuf, vt);
    // fused attention
    attn_kernel<<<dim3(T_ / 16, H_, B_), 256, 0, stream>>>(qkvbuf, vt, bias, mask, attn_out, ybuf);
    // proj + residual*ls1 -> x1
    gemm_kernel<2><<<dim3(C_ / 128, NROW / 128), 256, 0, stream>>>(
        ybuf, projw_b, projb, x1, nullptr, x, ls1, C_, C_);
    // LN2
    ln_kernel<<<NROW, 256, 0, stream>>>(x1, ln2g, ln2b, xn);
    // MLP1 + gelu
    gemm_kernel<1><<<dim3(HID_ / 128, NROW / 128), 256, 0, stream>>>(
        xn, w1_b, b1, nullptr, g, nullptr, nullptr, HID_, C_);
    // MLP2 + residual*ls2 -> out
    gemm_kernel<2><<<dim3(C_ / 128, NROW / 128), 256, 0, stream>>>(
        g, w2_b, b2, outx, nullptr, x1, ls2, C_, HID_);
}

// Round 14
// 432.050 us; speedup vs baseline: 1.0768x; 1.0768x over previous
//
#include <hip/hip_runtime.h>
#include <hip/hip_bf16.h>
#include <math.h>

#define B_ 2
#define T_ 2048
#define C_ 768
#define H_ 12
#define D_ 64
#define HID_ 3072
#define NROW 4096   // B*T
#define N3C 2304    // 3*C

typedef short bf16x8 __attribute__((ext_vector_type(8)));
typedef float f32x4 __attribute__((ext_vector_type(4)));
typedef unsigned short u16;
typedef unsigned int u32;

__device__ inline u16 f2bf(float f) {
    u32 u = __float_as_uint(f);
    u32 r = (u + 0x7fffu + ((u >> 16) & 1u)) >> 16;  // RNE
    return (u16)r;
}

// ---------------- fused weight convert: all 4 weight matrices in one launch ----------------
__global__ __launch_bounds__(256) void cvt4_kernel(const float* __restrict__ s0, u16* __restrict__ d0, int n0,
                                                   const float* __restrict__ s1, u16* __restrict__ d1, int n1,
                                                   const float* __restrict__ s2, u16* __restrict__ d2, int n2,
                                                   const float* __restrict__ s3, u16* __restrict__ d3, int n3) {
    int i = (blockIdx.x * 256 + threadIdx.x) * 4;
    const float* s;
    u16* d;
    if (i < n0) { s = s0; d = d0; }
    else if ((i -= n0) < n1) { s = s1; d = d1; }
    else if ((i -= n1) < n2) { s = s2; d = d2; }
    else if ((i -= n2) < n3) { s = s3; d = d3; }
    else return;
    float4 v = *(const float4*)(s + i);
    ushort4 o;
    o.x = f2bf(v.x); o.y = f2bf(v.y); o.z = f2bf(v.z); o.w = f2bf(v.w);
    *(ushort4*)(d + i) = o;
}

// ---------------- LayerNorm (f32 in, bf16 out), one block per row ----------------
__global__ __launch_bounds__(256) void ln_kernel(const float* __restrict__ x,
                                                 const float* __restrict__ g,
                                                 const float* __restrict__ b,
                                                 u16* __restrict__ out) {
    int row = blockIdx.x, t = threadIdx.x;
    const float* xr = x + (size_t)row * C_;
    float v[3], s = 0.f, sq = 0.f;
#pragma unroll
    for (int i = 0; i < 3; i++) {
        v[i] = xr[i * 256 + t];
        s += v[i]; sq += v[i] * v[i];
    }
    for (int m = 32; m; m >>= 1) { s += __shfl_xor(s, m); sq += __shfl_xor(sq, m); }
    __shared__ float ss[4], ssq[4];
    int wid = t >> 6;
    if ((t & 63) == 0) { ss[wid] = s; ssq[wid] = sq; }
    __syncthreads();
    s = ss[0] + ss[1] + ss[2] + ss[3];
    sq = ssq[0] + ssq[1] + ssq[2] + ssq[3];
    float mu = s * (1.f / C_);
    float var = sq * (1.f / C_) - mu * mu;
    float rstd = rsqrtf(var + 1e-5f);
#pragma unroll
    for (int i = 0; i < 3; i++) {
        int c = i * 256 + t;
        out[(size_t)row * C_ + c] = f2bf((v[i] - mu) * rstd * g[c] + b[c]);
    }
}

// ---------------- bf16 MFMA GEMM (R12 version: reg-staged + XOR swizzle + prefetch) ----------------
// R13 lesson: DMA staging (even with correct two-sided swizzle) loses at small K
// because it is a depth-1 pipeline across barriers; reg-staging's cross-K-step
// prefetch overlaps HBM latency with MFMA. This is the measured best (~610 TF).
template <int EPI>
__global__ __launch_bounds__(256) void gemm_kernel(const u16* __restrict__ A,
                                                   const u16* __restrict__ W,
                                                   const float* __restrict__ bias,
                                                   float* __restrict__ outf,
                                                   u16* __restrict__ outb,
                                                   const float* __restrict__ res,
                                                   const float* __restrict__ ls,
                                                   int N, int K) {
    __shared__ u16 Alds[128 * 64];
    __shared__ u16 Blds[128 * 64];
    int tid = threadIdx.x;
    int m0 = blockIdx.y * 128, n0 = blockIdx.x * 128;
    int lane = tid & 63, wid = tid >> 6;
    int wr = wid >> 1, wc = wid & 1;
    int lr = lane & 15, lq = lane >> 4;

    f32x4 acc[4][4];
#pragma unroll
    for (int i = 0; i < 4; i++)
#pragma unroll
        for (int j = 0; j < 4; j++) acc[i][j] = (f32x4){0.f, 0.f, 0.f, 0.f};

    int nk = K >> 6;
    const u16* Ab = A + (size_t)m0 * K;
    const u16* Wb = W + (size_t)n0 * K;
    bf16x8 ra[4], rb[4];
#pragma unroll
    for (int i = 0; i < 4; i++) {
        int c = tid + i * 256, row = c >> 3, j = c & 7;
        ra[i] = *(const bf16x8*)(Ab + (size_t)row * K + j * 8);
        rb[i] = *(const bf16x8*)(Wb + (size_t)row * K + j * 8);
    }
    for (int kt = 0; kt < nk; ++kt) {
        __syncthreads();
#pragma unroll
        for (int i = 0; i < 4; i++) {
            int c = tid + i * 256, row = c >> 3, j = c & 7;
            int off = row * 64 + ((j ^ (row & 7)) << 3);   // XOR-swizzled 16B blocks
            *(bf16x8*)(Alds + off) = ra[i];
            *(bf16x8*)(Blds + off) = rb[i];
        }
        __syncthreads();
        if (kt + 1 < nk) {
            int k0 = (kt + 1) << 6;
#pragma unroll
            for (int i = 0; i < 4; i++) {
                int c = tid + i * 256, row = c >> 3, j = c & 7;
                ra[i] = *(const bf16x8*)(Ab + (size_t)row * K + k0 + j * 8);
                rb[i] = *(const bf16x8*)(Wb + (size_t)row * K + k0 + j * 8);
            }
        }
#pragma unroll
        for (int s = 0; s < 2; s++) {
            bf16x8 af[4], bw[4];
#pragma unroll
            for (int i = 0; i < 4; i++) {
                int arow = wr * 64 + i * 16 + lr;
                af[i] = *(const bf16x8*)(Alds + arow * 64 + (((4 * s + lq) ^ (arow & 7)) << 3));
                int brow = wc * 64 + i * 16 + lr;
                bw[i] = *(const bf16x8*)(Blds + brow * 64 + (((4 * s + lq) ^ (brow & 7)) << 3));
            }
#pragma unroll
            for (int i = 0; i < 4; i++)
#pragma unroll
                for (int j = 0; j < 4; j++)
                    acc[i][j] = __builtin_amdgcn_mfma_f32_16x16x32_bf16(af[i], bw[j], acc[i][j], 0, 0, 0);
        }
    }
#pragma unroll
    for (int i = 0; i < 4; i++) {
#pragma unroll
        for (int j = 0; j < 4; j++) {
#pragma unroll
            for (int r = 0; r < 4; r++) {
                int gm = m0 + wr * 64 + i * 16 + lq * 4 + r;
                int gn = n0 + wc * 64 + j * 16 + lr;
                float val = acc[i][j][r] + bias[gn];
                if (EPI == 0) {
                    outb[(size_t)gm * N + gn] = f2bf(val);
                } else if (EPI == 1) {
                    float gl = 0.5f * val * (1.f + erff(val * 0.70710678118654752f));
                    outb[(size_t)gm * N + gn] = f2bf(gl);
                } else {
                    outf[(size_t)gm * N + gn] = res[(size_t)gm * N + gn] + ls[gn] * val;
                }
            }
        }
    }
}

// ---------------- V transpose: qkv_buf v-part -> Vt [B,H,D,T] ----------------
__global__ __launch_bounds__(256) void vtrans_kernel(const u16* __restrict__ qkv,
                                                     u16* __restrict__ vt) {
    __shared__ u16 tile[64 * 72];
    int t0 = blockIdx.x * 64, h = blockIdx.y, b = blockIdx.z;
    int tid = threadIdx.x;
#pragma unroll
    for (int i = 0; i < 2; i++) {
        int c = tid + i * 256, tr = c >> 3, j = c & 7;
        bf16x8 v = *(const bf16x8*)(qkv + (size_t)(b * T_ + t0 + tr) * N3C + 1536 + h * 64 + j * 8);
        *(bf16x8*)(tile + tr * 72 + j * 8) = v;
    }
    __syncthreads();
#pragma unroll
    for (int i = 0; i < 2; i++) {
        int c = tid + i * 256, d = c >> 3, tj = c & 7;
        bf16x8 o;
#pragma unroll
        for (int k = 0; k < 8; k++) o[k] = (short)tile[(tj * 8 + k) * 72 + d];
        *(bf16x8*)(vt + (size_t)((b * H_ + h) * 64 + d) * T_ + t0 + tj * 8) = o;
    }
}

// ---------------- fused attention (R10 winner: R6 structure + NT streams) ----------------
__global__ __launch_bounds__(256, 2) void attn_kernel(const u16* __restrict__ qkv,
                                                      const u16* __restrict__ vt,
                                                      const float* __restrict__ bias,
                                                      const float* __restrict__ mask,
                                                      float* __restrict__ attn_out,
                                                      u16* __restrict__ ybuf) {
    __shared__ u16 S[16 * 2048];     // bf16 scaled logits, then bf16 P in place
    __shared__ float rinv_lds[16];
    char* Sb = (char*)S;
    int qt = blockIdx.x, h = blockIdx.y, b = blockIdx.z;
    int tid = threadIdx.x, lane = tid & 63, wid = tid >> 6;
    int lr = lane & 15, lq = lane >> 4;
    int q0 = qt * 16;
    size_t bh = (size_t)(b * H_ + h);
    const float scale = 0.125f;

    // ---- A1: S = bf16(QK^T * scale) via swapped mfma(K,Q); wave w owns cols w*512.. ----
    const u16* qp = qkv + (size_t)(b * T_ + q0 + lr) * N3C + h * 64;
    bf16x8 qa0 = *(const bf16x8*)(qp + lq * 8);
    bf16x8 qa1 = *(const bf16x8*)(qp + 32 + lq * 8);
    const u16* kbase = qkv + (size_t)(b * T_ + wid * 512 + lr) * N3C + 768 + h * 64 + lq * 8;
#pragma unroll 4
    for (int ct = 0; ct < 32; ++ct) {
        bf16x8 kf0 = *(const bf16x8*)(kbase + (size_t)ct * 16 * N3C);
        bf16x8 kf1 = *(const bf16x8*)(kbase + (size_t)ct * 16 * N3C + 32);
        f32x4 a = (f32x4){0.f, 0.f, 0.f, 0.f};
        a = __builtin_amdgcn_mfma_f32_16x16x32_bf16(kf0, qa0, a, 0, 0, 0);
        a = __builtin_amdgcn_mfma_f32_16x16x32_bf16(kf1, qa1, a, 0, 0, 0);
        int colbase = wid * 512 + ct * 16;   // lane holds S[lr][colbase+lq*4 ..+3]
        ushort4 pk;
        pk.x = f2bf(a[0] * scale);
        pk.y = f2bf(a[1] * scale);
        pk.z = f2bf(a[2] * scale);
        pk.w = f2bf(a[3] * scale);
        *(ushort4*)(Sb + (((u32)lr * 4096 + 2 * colbase + 8 * lq) ^ ((lr & 7) << 4))) = pk;
    }
    __syncthreads();

    // ---- A2: P = exp(S + bias + mask), rows batched; bias via NT loads ----
    const float* bb = bias + (bh * T_ + q0 + wid * 4) * T_;
    const float* mb = mask + ((size_t)b * T_ + q0 + wid * 4) * T_;
    float lsum4[4] = {0.f, 0.f, 0.f, 0.f};
#pragma unroll
    for (int ch = 0; ch < 8; ++ch) {
        int col = ch * 256 + lane * 4;           // 64 lanes = 1KB contiguous per row
        f32x4 b4[4];
        float4 m4[4];
#pragma unroll
        for (int rr = 0; rr < 4; ++rr) {         // 8 independent dwordx4 loads issue here
            b4[rr] = __builtin_nontemporal_load((const f32x4*)(bb + (size_t)rr * T_ + col));
            m4[rr] = *(const float4*)(mb + (size_t)rr * T_ + col);
        }
#pragma unroll
        for (int rr = 0; rr < 4; ++rr) {
            int r = wid * 4 + rr;
            u32 addr = ((u32)r * 4096 + (u32)col * 2) ^ ((u32)(r & 7) << 4);
            uint2 s2 = *(const uint2*)(Sb + addr);
            float e0 = __expf(__uint_as_float(s2.x << 16) + b4[rr][0] + m4[rr].x);
            float e1 = __expf(__uint_as_float(s2.x & 0xffff0000u) + b4[rr][1] + m4[rr].y);
            float e2 = __expf(__uint_as_float(s2.y << 16) + b4[rr][2] + m4[rr].z);
            float e3 = __expf(__uint_as_float(s2.y & 0xffff0000u) + b4[rr][3] + m4[rr].w);
            lsum4[rr] += (e0 + e1) + (e2 + e3);
            uint2 o;
            o.x = ((u32)f2bf(e1) << 16) | (u32)f2bf(e0);
            o.y = ((u32)f2bf(e3) << 16) | (u32)f2bf(e2);
            *(uint2*)(Sb + addr) = o;                // in-place bf16 P
        }
    }
    float rinv_r[4];
#pragma unroll
    for (int rr = 0; rr < 4; ++rr) {
        float ls = lsum4[rr];
        for (int m = 32; m; m >>= 1) ls += __shfl_xor(ls, m);
        rinv_r[rr] = 1.f / ls;
        if (lane == 0) rinv_lds[wid * 4 + rr] = rinv_r[rr];
    }
    __syncthreads();

    // ---- A3: attn_out = P * rinv via NT stores (write-once stream) ----
    float* ao_base = attn_out + (bh * T_ + q0 + wid * 4) * T_;
#pragma unroll
    for (int ch = 0; ch < 8; ++ch) {
        int col = ch * 256 + lane * 4;
#pragma unroll
        for (int rr = 0; rr < 4; ++rr) {
            int r = wid * 4 + rr;
            u32 addr = ((u32)r * 4096 + (u32)col * 2) ^ ((u32)(r & 7) << 4);
            uint2 s2 = *(const uint2*)(Sb + addr);
            float rv = rinv_r[rr];
            f32x4 o;
            o[0] = __uint_as_float(s2.x << 16) * rv;
            o[1] = __uint_as_float(s2.x & 0xffff0000u) * rv;
            o[2] = __uint_as_float(s2.y << 16) * rv;
            o[3] = __uint_as_float(s2.y & 0xffff0000u) * rv;
            __builtin_nontemporal_store(o, (f32x4*)(ao_base + (size_t)rr * T_ + col));
        }
    }

    // ---- C: y = (P @ V) * rinv; wave w owns d-cols 16w..16w+15 ----
    f32x4 acc = (f32x4){0.f, 0.f, 0.f, 0.f};
    const u16* vtp = vt + (bh * 64 + wid * 16 + lr) * (size_t)T_ + lq * 8;
#pragma unroll 4
    for (int ks = 0; ks < 64; ++ks) {
        bf16x8 pf = *(const bf16x8*)(Sb + (((u32)lr * 4096 + ks * 64 + lq * 16) ^ ((lr & 7) << 4)));
        bf16x8 vf = *(const bf16x8*)(vtp + ks * 32);
        acc = __builtin_amdgcn_mfma_f32_16x16x32_bf16(pf, vf, acc, 0, 0, 0);
    }
#pragma unroll
    for (int r = 0; r < 4; r++) {
        int row = lq * 4 + r;
        float y = acc[r] * rinv_lds[row];
        ybuf[(size_t)(b * T_ + q0 + row) * C_ + h * 64 + wid * 16 + lr] = f2bf(y);
    }
}

// ---------------- host ----------------
extern "C" void kernel_launch(void* const* d_in, const int* in_sizes, int n_in,
                              void* d_out, int out_size, void* d_ws, size_t ws_size,
                              hipStream_t stream) {
    const float* x = (const float*)d_in[0];
    const float* mask = (const float*)d_in[1];
    const float* bias = (const float*)d_in[2];
    const float* ln1g = (const float*)d_in[3];
    const float* ln1b = (const float*)d_in[4];
    const float* qkvw = (const float*)d_in[5];
    const float* qkvb = (const float*)d_in[6];
    const float* projw = (const float*)d_in[7];
    const float* projb = (const float*)d_in[8];
    const float* ls1 = (const float*)d_in[9];
    const float* ln2g = (const float*)d_in[10];
    const float* ln2b = (const float*)d_in[11];
    const float* w1 = (const float*)d_in[12];
    const float* b1 = (const float*)d_in[13];
    const float* w2 = (const float*)d_in[14];
    const float* b2 = (const float*)d_in[15];
    const float* ls2 = (const float*)d_in[16];

    char* ws = (char*)d_ws;
    size_t off = 0;
    u16* qkvw_b = (u16*)(ws + off); off += (size_t)N3C * C_ * 2;
    u16* projw_b = (u16*)(ws + off); off += (size_t)C_ * C_ * 2;
    u16* w1_b = (u16*)(ws + off); off += (size_t)HID_ * C_ * 2;
    u16* w2_b = (u16*)(ws + off); off += (size_t)C_ * HID_ * 2;
    u16* xn = (u16*)(ws + off); off += (size_t)NROW * C_ * 2;          // reused as hn after attn
    u16* qkvbuf = (u16*)(ws + off); off += (size_t)NROW * N3C * 2;     // } contiguous; reused as
    u16* vt = (u16*)(ws + off); off += (size_t)B_ * H_ * D_ * T_ * 2;  // } g [4096,3072] after attn
    u16* g = qkvbuf;
    u16* ybuf = (u16*)(ws + off); off += (size_t)NROW * C_ * 2;
    float* x1 = (float*)(ws + off); off += (size_t)NROW * C_ * 4;
    (void)ws_size; (void)n_in; (void)in_sizes; (void)out_size;

    float* outx = (float*)d_out;
    float* attn_out = outx + (size_t)NROW * C_;

    // weights -> bf16 (single fused launch)
    {
        int n0 = N3C * C_, n1 = C_ * C_, n2 = HID_ * C_, n3 = C_ * HID_;
        int total = n0 + n1 + n2 + n3;
        cvt4_kernel<<<(total / 4 + 255) / 256, 256, 0, stream>>>(
            qkvw, qkvw_b, n0, projw, projw_b, n1, w1, w1_b, n2, w2, w2_b, n3);
    }

    // LN1
    ln_kernel<<<NROW, 256, 0, stream>>>(x, ln1g, ln1b, xn);
    // QKV
    gemm_kernel<0><<<dim3(N3C / 128, NROW / 128), 256, 0, stream>>>(
        xn, qkvw_b, qkvb, nullptr, qkvbuf, nullptr, nullptr, N3C, C_);
    // V transpose
    vtrans_kernel<<<dim3(T_ / 64, H_, B_), 256, 0, stream>>>(qkvbuf, vt);
    // fused attention
    attn_kernel<<<dim3(T_ / 16, H_, B_), 256, 0, stream>>>(qkvbuf, vt, bias, mask, attn_out, ybuf);
    // proj + residual*ls1 -> x1
    gemm_kernel<2><<<dim3(C_ / 128, NROW / 128), 256, 0, stream>>>(
        ybuf, projw_b, projb, x1, nullptr, x, ls1, C_, C_);
    // LN2
    ln_kernel<<<NROW, 256, 0, stream>>>(x1, ln2g, ln2b, xn);
    // MLP1 + gelu
    gemm_kernel<1><<<dim3(HID_ / 128, NROW / 128), 256, 0, stream>>>(
        xn, w1_b, b1, nullptr, g, nullptr, nullptr, HID_, C_);
    // MLP2 + residual*ls2 -> out
    gemm_kernel<2><<<dim3(C_ / 128, NROW / 128), 256, 0, stream>>>(
        g, w2_b, b2, outx, nullptr, x1, ls2, C_, HID_);
}

// Round 15
// 429.447 us; speedup vs baseline: 1.0833x; 1.0061x over previous
//
#include <hip/hip_runtime.h>
#include <hip/hip_bf16.h>
#include <math.h>

#define B_ 2
#define T_ 2048
#define C_ 768
#define H_ 12
#define D_ 64
#define HID_ 3072
#define NROW 4096   // B*T
#define N3C 2304    // 3*C

typedef short bf16x8 __attribute__((ext_vector_type(8)));
typedef float f32x4 __attribute__((ext_vector_type(4)));
typedef unsigned short u16;
typedef unsigned int u32;

__device__ inline u16 f2bf(float f) {
    u32 u = __float_as_uint(f);
    u32 r = (u + 0x7fffu + ((u >> 16) & 1u)) >> 16;  // RNE
    return (u16)r;
}

// ---------------- fused weight convert: all 4 weight matrices in one launch ----------------
__global__ __launch_bounds__(256) void cvt4_kernel(const float* __restrict__ s0, u16* __restrict__ d0, int n0,
                                                   const float* __restrict__ s1, u16* __restrict__ d1, int n1,
                                                   const float* __restrict__ s2, u16* __restrict__ d2, int n2,
                                                   const float* __restrict__ s3, u16* __restrict__ d3, int n3) {
    int i = (blockIdx.x * 256 + threadIdx.x) * 4;
    const float* s;
    u16* d;
    if (i < n0) { s = s0; d = d0; }
    else if ((i -= n0) < n1) { s = s1; d = d1; }
    else if ((i -= n1) < n2) { s = s2; d = d2; }
    else if ((i -= n2) < n3) { s = s3; d = d3; }
    else return;
    float4 v = *(const float4*)(s + i);
    ushort4 o;
    o.x = f2bf(v.x); o.y = f2bf(v.y); o.z = f2bf(v.z); o.w = f2bf(v.w);
    *(ushort4*)(d + i) = o;
}

// ---------------- LayerNorm (f32 in, bf16 out), one block per row ----------------
__global__ __launch_bounds__(256) void ln_kernel(const float* __restrict__ x,
                                                 const float* __restrict__ g,
                                                 const float* __restrict__ b,
                                                 u16* __restrict__ out) {
    int row = blockIdx.x, t = threadIdx.x;
    const float* xr = x + (size_t)row * C_;
    float v[3], s = 0.f, sq = 0.f;
#pragma unroll
    for (int i = 0; i < 3; i++) {
        v[i] = xr[i * 256 + t];
        s += v[i]; sq += v[i] * v[i];
    }
    for (int m = 32; m; m >>= 1) { s += __shfl_xor(s, m); sq += __shfl_xor(sq, m); }
    __shared__ float ss[4], ssq[4];
    int wid = t >> 6;
    if ((t & 63) == 0) { ss[wid] = s; ssq[wid] = sq; }
    __syncthreads();
    s = ss[0] + ss[1] + ss[2] + ss[3];
    sq = ssq[0] + ssq[1] + ssq[2] + ssq[3];
    float mu = s * (1.f / C_);
    float var = sq * (1.f / C_) - mu * mu;
    float rstd = rsqrtf(var + 1e-5f);
#pragma unroll
    for (int i = 0; i < 3; i++) {
        int c = i * 256 + t;
        out[(size_t)row * C_ + c] = f2bf((v[i] - mu) * rstd * g[c] + b[c]);
    }
}

// ---------------- bf16 MFMA GEMM (128x128, reg-staged + XOR swizzle + prefetch) ----------------
template <int EPI>
__global__ __launch_bounds__(256) void gemm_kernel(const u16* __restrict__ A,
                                                   const u16* __restrict__ W,
                                                   const float* __restrict__ bias,
                                                   float* __restrict__ outf,
                                                   u16* __restrict__ outb,
                                                   const float* __restrict__ res,
                                                   const float* __restrict__ ls,
                                                   int N, int K) {
    __shared__ u16 Alds[128 * 64];
    __shared__ u16 Blds[128 * 64];
    int tid = threadIdx.x;
    int m0 = blockIdx.y * 128, n0 = blockIdx.x * 128;
    int lane = tid & 63, wid = tid >> 6;
    int wr = wid >> 1, wc = wid & 1;
    int lr = lane & 15, lq = lane >> 4;

    f32x4 acc[4][4];
#pragma unroll
    for (int i = 0; i < 4; i++)
#pragma unroll
        for (int j = 0; j < 4; j++) acc[i][j] = (f32x4){0.f, 0.f, 0.f, 0.f};

    int nk = K >> 6;
    const u16* Ab = A + (size_t)m0 * K;
    const u16* Wb = W + (size_t)n0 * K;
    bf16x8 ra[4], rb[4];
#pragma unroll
    for (int i = 0; i < 4; i++) {
        int c = tid + i * 256, row = c >> 3, j = c & 7;
        ra[i] = *(const bf16x8*)(Ab + (size_t)row * K + j * 8);
        rb[i] = *(const bf16x8*)(Wb + (size_t)row * K + j * 8);
    }
    for (int kt = 0; kt < nk; ++kt) {
        __syncthreads();
#pragma unroll
        for (int i = 0; i < 4; i++) {
            int c = tid + i * 256, row = c >> 3, j = c & 7;
            int off = row * 64 + ((j ^ (row & 7)) << 3);   // XOR-swizzled 16B blocks
            *(bf16x8*)(Alds + off) = ra[i];
            *(bf16x8*)(Blds + off) = rb[i];
        }
        __syncthreads();
        if (kt + 1 < nk) {
            int k0 = (kt + 1) << 6;
#pragma unroll
            for (int i = 0; i < 4; i++) {
                int c = tid + i * 256, row = c >> 3, j = c & 7;
                ra[i] = *(const bf16x8*)(Ab + (size_t)row * K + k0 + j * 8);
                rb[i] = *(const bf16x8*)(Wb + (size_t)row * K + k0 + j * 8);
            }
        }
#pragma unroll
        for (int s = 0; s < 2; s++) {
            bf16x8 af[4], bw[4];
#pragma unroll
            for (int i = 0; i < 4; i++) {
                int arow = wr * 64 + i * 16 + lr;
                af[i] = *(const bf16x8*)(Alds + arow * 64 + (((4 * s + lq) ^ (arow & 7)) << 3));
                int brow = wc * 64 + i * 16 + lr;
                bw[i] = *(const bf16x8*)(Blds + brow * 64 + (((4 * s + lq) ^ (brow & 7)) << 3));
            }
#pragma unroll
            for (int i = 0; i < 4; i++)
#pragma unroll
                for (int j = 0; j < 4; j++)
                    acc[i][j] = __builtin_amdgcn_mfma_f32_16x16x32_bf16(af[i], bw[j], acc[i][j], 0, 0, 0);
        }
    }
#pragma unroll
    for (int i = 0; i < 4; i++) {
#pragma unroll
        for (int j = 0; j < 4; j++) {
#pragma unroll
            for (int r = 0; r < 4; r++) {
                int gm = m0 + wr * 64 + i * 16 + lq * 4 + r;
                int gn = n0 + wc * 64 + j * 16 + lr;
                float val = acc[i][j][r] + bias[gn];
                if (EPI == 0) {
                    outb[(size_t)gm * N + gn] = f2bf(val);
                } else if (EPI == 1) {
                    float gl = 0.5f * val * (1.f + erff(val * 0.70710678118654752f));
                    outb[(size_t)gm * N + gn] = f2bf(gl);
                } else {
                    outf[(size_t)gm * N + gn] = res[(size_t)gm * N + gn] + ls[gn] * val;
                }
            }
        }
    }
}

// ---------------- bf16 MFMA GEMM, BN=64 variant (128x64 tile) ----------------
// For N=768 outputs (proj, MLP2): 128x128 gives only 192 blocks on 256 CUs
// (64 CUs idle, 4 waves/CU on the rest). 128x64 -> 384 blocks, all CUs busy.
// Same staging/swizzle/prefetch pattern; 4 waves as 2x2 of 64x32, acc[4][2].
template <int EPI>
__global__ __launch_bounds__(256) void gemm_n64_kernel(const u16* __restrict__ A,
                                                       const u16* __restrict__ W,
                                                       const float* __restrict__ bias,
                                                       float* __restrict__ outf,
                                                       u16* __restrict__ outb,
                                                       const float* __restrict__ res,
                                                       const float* __restrict__ ls,
                                                       int N, int K) {
    __shared__ u16 Alds[128 * 64];   // 16KB
    __shared__ u16 Blds[64 * 64];    // 8KB
    int tid = threadIdx.x;
    int m0 = blockIdx.y * 128, n0 = blockIdx.x * 64;
    int lane = tid & 63, wid = tid >> 6;
    int wr = wid >> 1, wc = wid & 1;   // wave covers rows wr*64..+63, cols wc*32..+31
    int lr = lane & 15, lq = lane >> 4;

    f32x4 acc[4][2];
#pragma unroll
    for (int i = 0; i < 4; i++)
#pragma unroll
        for (int j = 0; j < 2; j++) acc[i][j] = (f32x4){0.f, 0.f, 0.f, 0.f};

    int nk = K >> 6;
    const u16* Ab = A + (size_t)m0 * K;
    const u16* Wb = W + (size_t)n0 * K;
    bf16x8 ra[4], rb[2];
#pragma unroll
    for (int i = 0; i < 4; i++) {
        int c = tid + i * 256, row = c >> 3, j = c & 7;
        ra[i] = *(const bf16x8*)(Ab + (size_t)row * K + j * 8);
    }
#pragma unroll
    for (int i = 0; i < 2; i++) {
        int c = tid + i * 256, row = c >> 3, j = c & 7;
        rb[i] = *(const bf16x8*)(Wb + (size_t)row * K + j * 8);
    }
    for (int kt = 0; kt < nk; ++kt) {
        __syncthreads();
#pragma unroll
        for (int i = 0; i < 4; i++) {
            int c = tid + i * 256, row = c >> 3, j = c & 7;
            *(bf16x8*)(Alds + row * 64 + ((j ^ (row & 7)) << 3)) = ra[i];
        }
#pragma unroll
        for (int i = 0; i < 2; i++) {
            int c = tid + i * 256, row = c >> 3, j = c & 7;
            *(bf16x8*)(Blds + row * 64 + ((j ^ (row & 7)) << 3)) = rb[i];
        }
        __syncthreads();
        if (kt + 1 < nk) {
            int k0 = (kt + 1) << 6;
#pragma unroll
            for (int i = 0; i < 4; i++) {
                int c = tid + i * 256, row = c >> 3, j = c & 7;
                ra[i] = *(const bf16x8*)(Ab + (size_t)row * K + k0 + j * 8);
            }
#pragma unroll
            for (int i = 0; i < 2; i++) {
                int c = tid + i * 256, row = c >> 3, j = c & 7;
                rb[i] = *(const bf16x8*)(Wb + (size_t)row * K + k0 + j * 8);
            }
        }
#pragma unroll
        for (int s = 0; s < 2; s++) {
            bf16x8 af[4], bw[2];
#pragma unroll
            for (int i = 0; i < 4; i++) {
                int arow = wr * 64 + i * 16 + lr;
                af[i] = *(const bf16x8*)(Alds + arow * 64 + (((4 * s + lq) ^ (arow & 7)) << 3));
            }
#pragma unroll
            for (int j = 0; j < 2; j++) {
                int brow = wc * 32 + j * 16 + lr;
                bw[j] = *(const bf16x8*)(Blds + brow * 64 + (((4 * s + lq) ^ (brow & 7)) << 3));
            }
#pragma unroll
            for (int i = 0; i < 4; i++)
#pragma unroll
                for (int j = 0; j < 2; j++)
                    acc[i][j] = __builtin_amdgcn_mfma_f32_16x16x32_bf16(af[i], bw[j], acc[i][j], 0, 0, 0);
        }
    }
#pragma unroll
    for (int i = 0; i < 4; i++) {
#pragma unroll
        for (int j = 0; j < 2; j++) {
#pragma unroll
            for (int r = 0; r < 4; r++) {
                int gm = m0 + wr * 64 + i * 16 + lq * 4 + r;
                int gn = n0 + wc * 32 + j * 16 + lr;
                float val = acc[i][j][r] + bias[gn];
                if (EPI == 0) {
                    outb[(size_t)gm * N + gn] = f2bf(val);
                } else if (EPI == 1) {
                    float gl = 0.5f * val * (1.f + erff(val * 0.70710678118654752f));
                    outb[(size_t)gm * N + gn] = f2bf(gl);
                } else {
                    outf[(size_t)gm * N + gn] = res[(size_t)gm * N + gn] + ls[gn] * val;
                }
            }
        }
    }
}

// ---------------- V transpose: qkv_buf v-part -> Vt [B,H,D,T] ----------------
__global__ __launch_bounds__(256) void vtrans_kernel(const u16* __restrict__ qkv,
                                                     u16* __restrict__ vt) {
    __shared__ u16 tile[64 * 72];
    int t0 = blockIdx.x * 64, h = blockIdx.y, b = blockIdx.z;
    int tid = threadIdx.x;
#pragma unroll
    for (int i = 0; i < 2; i++) {
        int c = tid + i * 256, tr = c >> 3, j = c & 7;
        bf16x8 v = *(const bf16x8*)(qkv + (size_t)(b * T_ + t0 + tr) * N3C + 1536 + h * 64 + j * 8);
        *(bf16x8*)(tile + tr * 72 + j * 8) = v;
    }
    __syncthreads();
#pragma unroll
    for (int i = 0; i < 2; i++) {
        int c = tid + i * 256, d = c >> 3, tj = c & 7;
        bf16x8 o;
#pragma unroll
        for (int k = 0; k < 8; k++) o[k] = (short)tile[(tj * 8 + k) * 72 + d];
        *(bf16x8*)(vt + (size_t)((b * H_ + h) * 64 + d) * T_ + t0 + tj * 8) = o;
    }
}

// ---------------- fused attention (R10 winner: R6 structure + NT streams) ----------------
__global__ __launch_bounds__(256, 2) void attn_kernel(const u16* __restrict__ qkv,
                                                      const u16* __restrict__ vt,
                                                      const float* __restrict__ bias,
                                                      const float* __restrict__ mask,
                                                      float* __restrict__ attn_out,
                                                      u16* __restrict__ ybuf) {
    __shared__ u16 S[16 * 2048];     // bf16 scaled logits, then bf16 P in place
    __shared__ float rinv_lds[16];
    char* Sb = (char*)S;
    int qt = blockIdx.x, h = blockIdx.y, b = blockIdx.z;
    int tid = threadIdx.x, lane = tid & 63, wid = tid >> 6;
    int lr = lane & 15, lq = lane >> 4;
    int q0 = qt * 16;
    size_t bh = (size_t)(b * H_ + h);
    const float scale = 0.125f;

    // ---- A1: S = bf16(QK^T * scale) via swapped mfma(K,Q); wave w owns cols w*512.. ----
    const u16* qp = qkv + (size_t)(b * T_ + q0 + lr) * N3C + h * 64;
    bf16x8 qa0 = *(const bf16x8*)(qp + lq * 8);
    bf16x8 qa1 = *(const bf16x8*)(qp + 32 + lq * 8);
    const u16* kbase = qkv + (size_t)(b * T_ + wid * 512 + lr) * N3C + 768 + h * 64 + lq * 8;
#pragma unroll 4
    for (int ct = 0; ct < 32; ++ct) {
        bf16x8 kf0 = *(const bf16x8*)(kbase + (size_t)ct * 16 * N3C);
        bf16x8 kf1 = *(const bf16x8*)(kbase + (size_t)ct * 16 * N3C + 32);
        f32x4 a = (f32x4){0.f, 0.f, 0.f, 0.f};
        a = __builtin_amdgcn_mfma_f32_16x16x32_bf16(kf0, qa0, a, 0, 0, 0);
        a = __builtin_amdgcn_mfma_f32_16x16x32_bf16(kf1, qa1, a, 0, 0, 0);
        int colbase = wid * 512 + ct * 16;   // lane holds S[lr][colbase+lq*4 ..+3]
        ushort4 pk;
        pk.x = f2bf(a[0] * scale);
        pk.y = f2bf(a[1] * scale);
        pk.z = f2bf(a[2] * scale);
        pk.w = f2bf(a[3] * scale);
        *(ushort4*)(Sb + (((u32)lr * 4096 + 2 * colbase + 8 * lq) ^ ((lr & 7) << 4))) = pk;
    }
    __syncthreads();

    // ---- A2: P = exp(S + bias + mask), rows batched; bias via NT loads ----
    const float* bb = bias + (bh * T_ + q0 + wid * 4) * T_;
    const float* mb = mask + ((size_t)b * T_ + q0 + wid * 4) * T_;
    float lsum4[4] = {0.f, 0.f, 0.f, 0.f};
#pragma unroll
    for (int ch = 0; ch < 8; ++ch) {
        int col = ch * 256 + lane * 4;           // 64 lanes = 1KB contiguous per row
        f32x4 b4[4];
        float4 m4[4];
#pragma unroll
        for (int rr = 0; rr < 4; ++rr) {         // 8 independent dwordx4 loads issue here
            b4[rr] = __builtin_nontemporal_load((const f32x4*)(bb + (size_t)rr * T_ + col));
            m4[rr] = *(const float4*)(mb + (size_t)rr * T_ + col);
        }
#pragma unroll
        for (int rr = 0; rr < 4; ++rr) {
            int r = wid * 4 + rr;
            u32 addr = ((u32)r * 4096 + (u32)col * 2) ^ ((u32)(r & 7) << 4);
            uint2 s2 = *(const uint2*)(Sb + addr);
            float e0 = __expf(__uint_as_float(s2.x << 16) + b4[rr][0] + m4[rr].x);
            float e1 = __expf(__uint_as_float(s2.x & 0xffff0000u) + b4[rr][1] + m4[rr].y);
            float e2 = __expf(__uint_as_float(s2.y << 16) + b4[rr][2] + m4[rr].z);
            float e3 = __expf(__uint_as_float(s2.y & 0xffff0000u) + b4[rr][3] + m4[rr].w);
            lsum4[rr] += (e0 + e1) + (e2 + e3);
            uint2 o;
            o.x = ((u32)f2bf(e1) << 16) | (u32)f2bf(e0);
            o.y = ((u32)f2bf(e3) << 16) | (u32)f2bf(e2);
            *(uint2*)(Sb + addr) = o;                // in-place bf16 P
        }
    }
    float rinv_r[4];
#pragma unroll
    for (int rr = 0; rr < 4; ++rr) {
        float ls = lsum4[rr];
        for (int m = 32; m; m >>= 1) ls += __shfl_xor(ls, m);
        rinv_r[rr] = 1.f / ls;
        if (lane == 0) rinv_lds[wid * 4 + rr] = rinv_r[rr];
    }
    __syncthreads();

    // ---- A3: attn_out = P * rinv via NT stores (write-once stream) ----
    float* ao_base = attn_out + (bh * T_ + q0 + wid * 4) * T_;
#pragma unroll
    for (int ch = 0; ch < 8; ++ch) {
        int col = ch * 256 + lane * 4;
#pragma unroll
        for (int rr = 0; rr < 4; ++rr) {
            int r = wid * 4 + rr;
            u32 addr = ((u32)r * 4096 + (u32)col * 2) ^ ((u32)(r & 7) << 4);
            uint2 s2 = *(const uint2*)(Sb + addr);
            float rv = rinv_r[rr];
            f32x4 o;
            o[0] = __uint_as_float(s2.x << 16) * rv;
            o[1] = __uint_as_float(s2.x & 0xffff0000u) * rv;
            o[2] = __uint_as_float(s2.y << 16) * rv;
            o[3] = __uint_as_float(s2.y & 0xffff0000u) * rv;
            __builtin_nontemporal_store(o, (f32x4*)(ao_base + (size_t)rr * T_ + col));
        }
    }

    // ---- C: y = (P @ V) * rinv; wave w owns d-cols 16w..16w+15 ----
    f32x4 acc = (f32x4){0.f, 0.f, 0.f, 0.f};
    const u16* vtp = vt + (bh * 64 + wid * 16 + lr) * (size_t)T_ + lq * 8;
#pragma unroll 4
    for (int ks = 0; ks < 64; ++ks) {
        bf16x8 pf = *(const bf16x8*)(Sb + (((u32)lr * 4096 + ks * 64 + lq * 16) ^ ((lr & 7) << 4)));
        bf16x8 vf = *(const bf16x8*)(vtp + ks * 32);
        acc = __builtin_amdgcn_mfma_f32_16x16x32_bf16(pf, vf, acc, 0, 0, 0);
    }
#pragma unroll
    for (int r = 0; r < 4; r++) {
        int row = lq * 4 + r;
        float y = acc[r] * rinv_lds[row];
        ybuf[(size_t)(b * T_ + q0 + row) * C_ + h * 64 + wid * 16 + lr] = f2bf(y);
    }
}

// ---------------- host ----------------
extern "C" void kernel_launch(void* const* d_in, const int* in_sizes, int n_in,
                              void* d_out, int out_size, void* d_ws, size_t ws_size,
                              hipStream_t stream) {
    const float* x = (const float*)d_in[0];
    const float* mask = (const float*)d_in[1];
    const float* bias = (const float*)d_in[2];
    const float* ln1g = (const float*)d_in[3];
    const float* ln1b = (const float*)d_in[4];
    const float* qkvw = (const float*)d_in[5];
    const float* qkvb = (const float*)d_in[6];
    const float* projw = (const float*)d_in[7];
    const float* projb = (const float*)d_in[8];
    const float* ls1 = (const float*)d_in[9];
    const float* ln2g = (const float*)d_in[10];
    const float* ln2b = (const float*)d_in[11];
    const float* w1 = (const float*)d_in[12];
    const float* b1 = (const float*)d_in[13];
    const float* w2 = (const float*)d_in[14];
    const float* b2 = (const float*)d_in[15];
    const float* ls2 = (const float*)d_in[16];

    char* ws = (char*)d_ws;
    size_t off = 0;
    u16* qkvw_b = (u16*)(ws + off); off += (size_t)N3C * C_ * 2;
    u16* projw_b = (u16*)(ws + off); off += (size_t)C_ * C_ * 2;
    u16* w1_b = (u16*)(ws + off); off += (size_t)HID_ * C_ * 2;
    u16* w2_b = (u16*)(ws + off); off += (size_t)C_ * HID_ * 2;
    u16* xn = (u16*)(ws + off); off += (size_t)NROW * C_ * 2;          // reused as hn after attn
    u16* qkvbuf = (u16*)(ws + off); off += (size_t)NROW * N3C * 2;     // } contiguous; reused as
    u16* vt = (u16*)(ws + off); off += (size_t)B_ * H_ * D_ * T_ * 2;  // } g [4096,3072] after attn
    u16* g = qkvbuf;
    u16* ybuf = (u16*)(ws + off); off += (size_t)NROW * C_ * 2;
    float* x1 = (float*)(ws + off); off += (size_t)NROW * C_ * 4;
    (void)ws_size; (void)n_in; (void)in_sizes; (void)out_size;

    float* outx = (float*)d_out;
    float* attn_out = outx + (size_t)NROW * C_;

    // weights -> bf16 (single fused launch)
    {
        int n0 = N3C * C_, n1 = C_ * C_, n2 = HID_ * C_, n3 = C_ * HID_;
        int total = n0 + n1 + n2 + n3;
        cvt4_kernel<<<(total / 4 + 255) / 256, 256, 0, stream>>>(
            qkvw, qkvw_b, n0, projw, projw_b, n1, w1, w1_b, n2, w2, w2_b, n3);
    }

    // LN1
    ln_kernel<<<NROW, 256, 0, stream>>>(x, ln1g, ln1b, xn);
    // QKV
    gemm_kernel<0><<<dim3(N3C / 128, NROW / 128), 256, 0, stream>>>(
        xn, qkvw_b, qkvb, nullptr, qkvbuf, nullptr, nullptr, N3C, C_);
    // V transpose
    vtrans_kernel<<<dim3(T_ / 64, H_, B_), 256, 0, stream>>>(qkvbuf, vt);
    // fused attention
    attn_kernel<<<dim3(T_ / 16, H_, B_), 256, 0, stream>>>(qkvbuf, vt, bias, mask, attn_out, ybuf);
    // proj + residual*ls1 -> x1  (BN=64: 384 blocks, full CU fill)
    gemm_n64_kernel<2><<<dim3(C_ / 64, NROW / 128), 256, 0, stream>>>(
        ybuf, projw_b, projb, x1, nullptr, x, ls1, C_, C_);
    // LN2
    ln_kernel<<<NROW, 256, 0, stream>>>(x1, ln2g, ln2b, xn);
    // MLP1 + gelu
    gemm_kernel<1><<<dim3(HID_ / 128, NROW / 128), 256, 0, stream>>>(
        xn, w1_b, b1, nullptr, g, nullptr, nullptr, HID_, C_);
    // MLP2 + residual*ls2 -> out  (BN=64: 384 blocks, full CU fill)
    gemm_n64_kernel<2><<<dim3(C_ / 64, NROW / 128), 256, 0, stream>>>(
        g, w2_b, b2, outx, nullptr, x1, ls2, C_, HID_);
}